// Round 2
// baseline (697.930 us; speedup 1.0000x reference)
//
#include <hip/hip_runtime.h>

// Per-pixel diagonal RNN, fp32 in/out.
// h_t = leaky_relu(W_ih*x_t + W_hh*h_{t-1} + b_hh), T=50, 2M independent pixels.
// Memory-bound: ~864 MB traffic -> ~137 us roofline at 6.3 TB/s achievable.

__global__ __launch_bounds__(256) void pixel_rnn_kernel(
    const float4* __restrict__ x,      // (T, nvec) vectors of 4 fp32
    const float4* __restrict__ wih,    // (nvec)
    const float4* __restrict__ whh,    // (nvec)
    const float4* __restrict__ bhh,    // (nvec)
    float4* __restrict__ out,          // (T, nvec)
    int nvec, int T)
{
    int i = blockIdx.x * blockDim.x + threadIdx.x;
    if (i >= nvec) return;

    // Weights: load once, keep in registers for the whole recurrence.
    float4 wi = wih[i];
    float4 wh = whh[i];
    float4 b  = bhh[i];

    float h0 = 0.f, h1 = 0.f, h2 = 0.f, h3 = 0.f;

    size_t idx = (size_t)i;
    size_t stride = (size_t)nvec;

#pragma unroll 2
    for (int t = 0; t < T; ++t) {
        float4 xv = x[idx];
        float v0 = fmaf(wh.x, h0, fmaf(wi.x, xv.x, b.x));
        float v1 = fmaf(wh.y, h1, fmaf(wi.y, xv.y, b.y));
        float v2 = fmaf(wh.z, h2, fmaf(wi.z, xv.z, b.z));
        float v3 = fmaf(wh.w, h3, fmaf(wi.w, xv.w, b.w));
        h0 = (v0 > 0.f) ? v0 : 0.01f * v0;
        h1 = (v1 > 0.f) ? v1 : 0.01f * v1;
        h2 = (v2 > 0.f) ? v2 : 0.01f * v2;
        h3 = (v3 > 0.f) ? v3 : 0.01f * v3;
        float4 ov = make_float4(h0, h1, h2, h3);
        out[idx] = ov;
        idx += stride;
    }
}

extern "C" void kernel_launch(void* const* d_in, const int* in_sizes, int n_in,
                              void* d_out, int out_size, void* d_ws, size_t ws_size,
                              hipStream_t stream) {
    const float4* x   = (const float4*)d_in[0];
    const float4* wih = (const float4*)d_in[1];
    const float4* whh = (const float4*)d_in[2];
    const float4* bhh = (const float4*)d_in[3];
    float4* out = (float4*)d_out;

    int npix = in_sizes[1];          // Z*H*W (W_ih element count) = 2,097,152
    int T    = in_sizes[0] / npix;   // 50
    int nvec = npix / 4;             // 4 fp32 per thread

    int block = 256;
    int grid = (nvec + block - 1) / block;
    pixel_rnn_kernel<<<grid, block, 0, stream>>>(x, wih, whh, bhh, out, nvec, T);
}